// Round 4
// baseline (433.929 us; speedup 1.0000x reference)
//
#include <hip/hip_runtime.h>

#define CC 8
#define HH 256
#define WW 512
#define KK 9
#define XF 268   // LDS floats per channel row (264 used: window [seg*256-4, seg*256+259])

__global__ __launch_bounds__(256, 4) void dynfilter_kernel(
    const float* __restrict__ x,
    const float* __restrict__ filt,
    const float* __restrict__ fbias,
    float* __restrict__ out)
{
    __shared__ __align__(16) float xs[2][CC][XF];

    const int tid = threadIdx.x;
    const int bid = blockIdx.x;          // 1024 = seg(2) * h(256) * n(2)
    const int seg = bid & 1;
    const int h   = (bid >> 1) & 255;
    const int n   = bid >> 9;

    const int pxg = tid & 127;           // 128 pixel-groups of 2 px
    const int cg  = tid >> 7;            // channel-group: 0 -> ch0-3, 1 -> ch4-7
    const int w0  = seg * 256 + (pxg << 1);

    const int lane32  = tid & 31;        // staging: 8 channels x 32 lanes
    const int cstage  = tid >> 5;
    const int wstage0 = seg * 256 - 4;
    const float* xcrow = x + ((size_t)(n * CC + cstage)) * ((size_t)HH * WW) + wstage0;

    const size_t HW = (size_t)HH * WW;
    const float* fbase = filt + ((size_t)(n * 81) * HH + h) * WW + w0;

    float acc[4][2];
    {
        const float2 fb = *(const float2*)(fbias + ((size_t)(n * HH + h)) * WW + w0);
        #pragma unroll
        for (int c = 0; c < 4; ++c) { acc[c][0] = fb.x; acc[c][1] = fb.y; }
    }

    // ---- prologue: stage row h-4 into buf 0 ----
    {
        const int hh = h - 4;
        const bool rowok = (hh >= 0);
        const float* src = xcrow + (size_t)hh * WW;
        float4 s0 = make_float4(0.f,0.f,0.f,0.f), s1 = s0, s2 = s0;
        int w;
        w = wstage0 + (lane32 << 2);
        if (rowok && (unsigned)w < (unsigned)WW) s0 = *(const float4*)(src + (lane32 << 2));
        w = wstage0 + ((lane32 + 32) << 2);
        if (rowok && (unsigned)w < (unsigned)WW) s1 = *(const float4*)(src + ((lane32 + 32) << 2));
        w = wstage0 + ((lane32 + 64) << 2);
        if (lane32 < 2 && rowok && (unsigned)w < (unsigned)WW) s2 = *(const float4*)(src + ((lane32 + 64) << 2));
        *(float4*)&xs[0][cstage][lane32 << 2] = s0;
        *(float4*)&xs[0][cstage][(lane32 + 32) << 2] = s1;
        if (lane32 < 2) *(float4*)&xs[0][cstage][(lane32 + 64) << 2] = s2;
    }
    __syncthreads();

    #pragma unroll
    for (int i = 0; i < KK; ++i) {
        const int buf = i & 1;

        // 1) filter taps for tap-row i: 9 coalesced float2 loads (the HBM-critical stream)
        float2 f[KK];
        #pragma unroll
        for (int j = 0; j < KK; ++j)
            f[j] = *(const float2*)(fbase + (size_t)(i * KK + j) * HW);

        // 2) issue next-row staging loads into named regs (in flight during compute)
        float4 s0 = make_float4(0.f,0.f,0.f,0.f), s1 = s0, s2 = s0;
        if (i < KK - 1) {
            const int hh = h - 4 + i + 1;
            const bool rowok = (unsigned)hh < (unsigned)HH;
            const float* src = xcrow + (size_t)hh * WW;
            int w;
            w = wstage0 + (lane32 << 2);
            if (rowok && (unsigned)w < (unsigned)WW) s0 = *(const float4*)(src + (lane32 << 2));
            w = wstage0 + ((lane32 + 32) << 2);
            if (rowok && (unsigned)w < (unsigned)WW) s1 = *(const float4*)(src + ((lane32 + 32) << 2));
            w = wstage0 + ((lane32 + 64) << 2);
            if (lane32 < 2 && rowok && (unsigned)w < (unsigned)WW) s2 = *(const float4*)(src + ((lane32 + 64) << 2));
        }

        // 3) compute from current buffer: window starts at LDS index 2*pxg (b64-aligned)
        #pragma unroll
        for (int c = 0; c < 4; ++c) {
            const float* xp = &xs[buf][(cg << 2) + c][pxg << 1];
            float xr[10];
            float2 v;
            v = *(const float2*)(xp + 0); xr[0] = v.x; xr[1] = v.y;
            v = *(const float2*)(xp + 2); xr[2] = v.x; xr[3] = v.y;
            v = *(const float2*)(xp + 4); xr[4] = v.x; xr[5] = v.y;
            v = *(const float2*)(xp + 6); xr[6] = v.x; xr[7] = v.y;
            v = *(const float2*)(xp + 8); xr[8] = v.x; xr[9] = v.y;
            #pragma unroll
            for (int j = 0; j < KK; ++j) {
                acc[c][0] = fmaf(f[j].x, xr[j],     acc[c][0]);
                acc[c][1] = fmaf(f[j].y, xr[j + 1], acc[c][1]);
            }
        }

        // 4) store staged row into the other buffer; single barrier per iter
        if (i < KK - 1) {
            *(float4*)&xs[buf ^ 1][cstage][lane32 << 2] = s0;
            *(float4*)&xs[buf ^ 1][cstage][(lane32 + 32) << 2] = s1;
            if (lane32 < 2) *(float4*)&xs[buf ^ 1][cstage][(lane32 + 64) << 2] = s2;
        }
        __syncthreads();
    }

    #pragma unroll
    for (int c = 0; c < 4; ++c) {
        *(float2*)(out + ((size_t)(n * CC + (cg << 2) + c) * HH + h) * WW + w0) =
            make_float2(acc[c][0], acc[c][1]);
    }
}

extern "C" void kernel_launch(void* const* d_in, const int* in_sizes, int n_in,
                              void* d_out, int out_size, void* d_ws, size_t ws_size,
                              hipStream_t stream) {
    const float* x  = (const float*)d_in[0];
    const float* f  = (const float*)d_in[1];
    const float* fb = (const float*)d_in[2];
    float* o = (float*)d_out;
    hipLaunchKernelGGL(dynfilter_kernel, dim3(1024), dim3(256), 0, stream,
                       x, f, fb, o);
}

// Round 5
// 258.276 us; speedup vs baseline: 1.6801x; 1.6801x over previous
//
#include <hip/hip_runtime.h>

#define CC 8
#define HH 256
#define WW 512
#define KK 9
#define XF 268   // LDS floats per channel row: window [seg*256-4, seg*256+260), 264 used

__global__ __launch_bounds__(256) void dynfilter_kernel(
    const float* __restrict__ x,
    const float* __restrict__ filt,
    const float* __restrict__ fbias,
    float* __restrict__ out)
{
    __shared__ __align__(16) float xs[2][CC][XF];

    const int tid = threadIdx.x;
    const int bid = blockIdx.x;          // 1024 = seg(2) * h(256) * n(2)
    const int seg = bid & 1;
    const int h   = (bid >> 1) & 255;
    const int n   = bid >> 9;

    const int pxg = tid & 127;           // 128 pixel-groups of 2 px
    const int cg  = tid >> 7;            // channel-group: 0 -> ch0-3, 1 -> ch4-7
    const int w0  = seg * 256 + (pxg << 1);

    const int lane32  = tid & 31;        // staging: 8 channels x 32 lanes
    const int cstage  = tid >> 5;
    const int wstage0 = seg * 256 - 4;
    const float* xcrow = x + ((size_t)(n * CC + cstage)) * ((size_t)HH * WW) + wstage0;

    const size_t HW = (size_t)HH * WW;
    const float* fptr = filt + ((size_t)(n * 81) * HH + h) * WW + w0;

    float acc[4][2];
    {
        const float2 fb = *(const float2*)(fbias + ((size_t)(n * HH + h)) * WW + w0);
        acc[0][0] = fb.x; acc[0][1] = fb.y;
        acc[1][0] = fb.x; acc[1][1] = fb.y;
        acc[2][0] = fb.x; acc[2][1] = fb.y;
        acc[3][0] = fb.x; acc[3][1] = fb.y;
    }

    // ---- prologue: stage row h-4 into buf 0 ----
    {
        const int hh = h - 4;
        const bool rowok = (hh >= 0);
        const float* src = xcrow + (size_t)hh * WW;
        float4 s0 = make_float4(0.f,0.f,0.f,0.f), s1 = s0, s2 = s0;
        int w;
        w = wstage0 + (lane32 << 2);
        if (rowok && (unsigned)w < (unsigned)WW) s0 = *(const float4*)(src + (lane32 << 2));
        w = wstage0 + ((lane32 + 32) << 2);
        if (rowok && (unsigned)w < (unsigned)WW) s1 = *(const float4*)(src + ((lane32 + 32) << 2));
        w = wstage0 + ((lane32 + 64) << 2);
        if (lane32 < 2 && rowok && (unsigned)w < (unsigned)WW) s2 = *(const float4*)(src + ((lane32 + 64) << 2));
        *(float4*)&xs[0][cstage][lane32 << 2] = s0;
        *(float4*)&xs[0][cstage][(lane32 + 32) << 2] = s1;
        if (lane32 < 2) *(float4*)&xs[0][cstage][(lane32 + 64) << 2] = s2;
    }
    __syncthreads();

    // ---- main loop over tap rows (ROLLED: no cross-iteration load hoisting) ----
    for (int i = 0; i < KK; ++i) {
        const int buf = i & 1;

        // 1) filter taps for tap-row i: 9 coalesced float2 loads (HBM-critical stream)
        float2 f0, f1, f2, f3, f4, f5, f6, f7, f8;
        {
            const float* fi = fptr + (size_t)i * KK * HW;
            f0 = *(const float2*)(fi + 0 * HW);
            f1 = *(const float2*)(fi + 1 * HW);
            f2 = *(const float2*)(fi + 2 * HW);
            f3 = *(const float2*)(fi + 3 * HW);
            f4 = *(const float2*)(fi + 4 * HW);
            f5 = *(const float2*)(fi + 5 * HW);
            f6 = *(const float2*)(fi + 6 * HW);
            f7 = *(const float2*)(fi + 7 * HW);
            f8 = *(const float2*)(fi + 8 * HW);
        }

        // 2) issue next-row staging loads (stay in flight during compute)
        float4 s0 = make_float4(0.f,0.f,0.f,0.f), s1 = s0, s2 = s0;
        if (i < KK - 1) {
            const int hh = h - 3 + i;
            const bool rowok = (unsigned)hh < (unsigned)HH;
            const float* src = xcrow + (size_t)hh * WW;
            int w;
            w = wstage0 + (lane32 << 2);
            if (rowok && (unsigned)w < (unsigned)WW) s0 = *(const float4*)(src + (lane32 << 2));
            w = wstage0 + ((lane32 + 32) << 2);
            if (rowok && (unsigned)w < (unsigned)WW) s1 = *(const float4*)(src + ((lane32 + 32) << 2));
            w = wstage0 + ((lane32 + 64) << 2);
            if (lane32 < 2 && rowok && (unsigned)w < (unsigned)WW) s2 = *(const float4*)(src + ((lane32 + 64) << 2));
        }

        // 3) compute from current buffer (window starts at LDS float index 2*pxg)
        #pragma unroll
        for (int c = 0; c < 4; ++c) {
            const float* xp = &xs[buf][(cg << 2) + c][pxg << 1];
            float2 v0 = *(const float2*)(xp + 0);
            float2 v1 = *(const float2*)(xp + 2);
            float2 v2 = *(const float2*)(xp + 4);
            float2 v3 = *(const float2*)(xp + 6);
            float2 v4 = *(const float2*)(xp + 8);
            float a0 = acc[c][0], a1 = acc[c][1];
            a0 = fmaf(f0.x, v0.x, a0);  a1 = fmaf(f0.y, v0.y, a1);
            a0 = fmaf(f1.x, v0.y, a0);  a1 = fmaf(f1.y, v1.x, a1);
            a0 = fmaf(f2.x, v1.x, a0);  a1 = fmaf(f2.y, v1.y, a1);
            a0 = fmaf(f3.x, v1.y, a0);  a1 = fmaf(f3.y, v2.x, a1);
            a0 = fmaf(f4.x, v2.x, a0);  a1 = fmaf(f4.y, v2.y, a1);
            a0 = fmaf(f5.x, v2.y, a0);  a1 = fmaf(f5.y, v3.x, a1);
            a0 = fmaf(f6.x, v3.x, a0);  a1 = fmaf(f6.y, v3.y, a1);
            a0 = fmaf(f7.x, v3.y, a0);  a1 = fmaf(f7.y, v4.x, a1);
            a0 = fmaf(f8.x, v4.x, a0);  a1 = fmaf(f8.y, v4.y, a1);
            acc[c][0] = a0; acc[c][1] = a1;
        }

        // 4) store staged row into the other buffer; single barrier per iter
        if (i < KK - 1) {
            *(float4*)&xs[buf ^ 1][cstage][lane32 << 2] = s0;
            *(float4*)&xs[buf ^ 1][cstage][(lane32 + 32) << 2] = s1;
            if (lane32 < 2) *(float4*)&xs[buf ^ 1][cstage][(lane32 + 64) << 2] = s2;
        }
        __syncthreads();
    }

    #pragma unroll
    for (int c = 0; c < 4; ++c) {
        *(float2*)(out + ((size_t)(n * CC + (cg << 2) + c) * HH + h) * WW + w0) =
            make_float2(acc[c][0], acc[c][1]);
    }
}

extern "C" void kernel_launch(void* const* d_in, const int* in_sizes, int n_in,
                              void* d_out, int out_size, void* d_ws, size_t ws_size,
                              hipStream_t stream) {
    const float* x  = (const float*)d_in[0];
    const float* f  = (const float*)d_in[1];
    const float* fb = (const float*)d_in[2];
    float* o = (float*)d_out;
    hipLaunchKernelGGL(dynfilter_kernel, dim3(1024), dim3(256), 0, stream,
                       x, f, fb, o);
}

// Round 6
// 139.021 us; speedup vs baseline: 3.1213x; 1.8578x over previous
//
#include <hip/hip_runtime.h>

#define CC 8
#define HH 256
#define WW 512
#define KK 9
#define XF 268   // LDS floats per channel row: window [seg*256-4, seg*256+260), 264 used

__global__ __launch_bounds__(256) void dynfilter_kernel(
    const float* __restrict__ x,
    const float* __restrict__ filt,
    const float* __restrict__ fbias,
    float* __restrict__ out)
{
    __shared__ __align__(16) float xs[2][CC][XF];

    const int tid = threadIdx.x;
    const int bid = blockIdx.x;          // 1024 = seg(2) * h(256) * n(2)
    const int seg = bid & 1;
    const int h   = (bid >> 1) & 255;
    const int n   = bid >> 9;

    const int pxg = tid & 127;           // 128 pixel-groups of 2 px
    const int cg  = tid >> 7;            // channel-group: 0 -> ch0-3, 1 -> ch4-7
    const int w0  = seg * 256 + (pxg << 1);

    const int lane32  = tid & 31;        // staging: 8 channels x 32 lanes
    const int cstage  = tid >> 5;
    const int wstage0 = seg * 256 - 4;
    const float* xcrow = x + ((size_t)(n * CC + cstage)) * ((size_t)HH * WW) + wstage0;

    const size_t HW = (size_t)HH * WW;
    const float* fptr = filt + ((size_t)(n * 81) * HH + h) * WW + w0;

    float acc[4][2];
    {
        const float2 fb = *(const float2*)(fbias + ((size_t)(n * HH + h)) * WW + w0);
        acc[0][0] = fb.x; acc[0][1] = fb.y;
        acc[1][0] = fb.x; acc[1][1] = fb.y;
        acc[2][0] = fb.x; acc[2][1] = fb.y;
        acc[3][0] = fb.x; acc[3][1] = fb.y;
    }

    // ---- prologue: stage row h-4 into buf 0 ----
    {
        const int hh = h - 4;
        const bool rowok = (hh >= 0);
        const float* src = xcrow + (size_t)hh * WW;
        float4 s0 = make_float4(0.f,0.f,0.f,0.f), s1 = s0, s2 = s0;
        int w;
        w = wstage0 + (lane32 << 2);
        if (rowok && (unsigned)w < (unsigned)WW) s0 = *(const float4*)(src + (lane32 << 2));
        w = wstage0 + ((lane32 + 32) << 2);
        if (rowok && (unsigned)w < (unsigned)WW) s1 = *(const float4*)(src + ((lane32 + 32) << 2));
        w = wstage0 + ((lane32 + 64) << 2);
        if (lane32 < 2 && rowok && (unsigned)w < (unsigned)WW) s2 = *(const float4*)(src + ((lane32 + 64) << 2));
        *(float4*)&xs[0][cstage][lane32 << 2] = s0;
        *(float4*)&xs[0][cstage][(lane32 + 32) << 2] = s1;
        if (lane32 < 2) *(float4*)&xs[0][cstage][(lane32 + 64) << 2] = s2;
    }
    __syncthreads();

    // ---- main loop over tap rows ----
    // CRITICAL: compiler auto-unrolls trip-count-9 loops, then hoists all 81
    // filter loads -> 256 VGPR + scratch spill (R3/R4/R5 all hit this).
    // unroll(disable) is the fix, not source-level rolling.
    #pragma clang loop unroll(disable)
    for (int i = 0; i < KK; ++i) {
        const int buf = i & 1;

        // 1) filter taps for tap-row i: 9 coalesced float2 loads (HBM-critical stream)
        float2 f0, f1, f2, f3, f4, f5, f6, f7, f8;
        {
            const float* fi = fptr + (size_t)i * KK * HW;
            f0 = *(const float2*)(fi + 0 * HW);
            f1 = *(const float2*)(fi + 1 * HW);
            f2 = *(const float2*)(fi + 2 * HW);
            f3 = *(const float2*)(fi + 3 * HW);
            f4 = *(const float2*)(fi + 4 * HW);
            f5 = *(const float2*)(fi + 5 * HW);
            f6 = *(const float2*)(fi + 6 * HW);
            f7 = *(const float2*)(fi + 7 * HW);
            f8 = *(const float2*)(fi + 8 * HW);
        }

        // 2) issue next-row staging loads (stay in flight during compute)
        float4 s0 = make_float4(0.f,0.f,0.f,0.f), s1 = s0, s2 = s0;
        if (i < KK - 1) {
            const int hh = h - 3 + i;
            const bool rowok = (unsigned)hh < (unsigned)HH;
            const float* src = xcrow + (size_t)hh * WW;
            int w;
            w = wstage0 + (lane32 << 2);
            if (rowok && (unsigned)w < (unsigned)WW) s0 = *(const float4*)(src + (lane32 << 2));
            w = wstage0 + ((lane32 + 32) << 2);
            if (rowok && (unsigned)w < (unsigned)WW) s1 = *(const float4*)(src + ((lane32 + 32) << 2));
            w = wstage0 + ((lane32 + 64) << 2);
            if (lane32 < 2 && rowok && (unsigned)w < (unsigned)WW) s2 = *(const float4*)(src + ((lane32 + 64) << 2));
        }

        // 3) compute from current buffer (window starts at LDS float index 2*pxg)
        #pragma unroll
        for (int c = 0; c < 4; ++c) {
            const float* xp = &xs[buf][(cg << 2) + c][pxg << 1];
            float2 v0 = *(const float2*)(xp + 0);
            float2 v1 = *(const float2*)(xp + 2);
            float2 v2 = *(const float2*)(xp + 4);
            float2 v3 = *(const float2*)(xp + 6);
            float2 v4 = *(const float2*)(xp + 8);
            float a0 = acc[c][0], a1 = acc[c][1];
            a0 = fmaf(f0.x, v0.x, a0);  a1 = fmaf(f0.y, v0.y, a1);
            a0 = fmaf(f1.x, v0.y, a0);  a1 = fmaf(f1.y, v1.x, a1);
            a0 = fmaf(f2.x, v1.x, a0);  a1 = fmaf(f2.y, v1.y, a1);
            a0 = fmaf(f3.x, v1.y, a0);  a1 = fmaf(f3.y, v2.x, a1);
            a0 = fmaf(f4.x, v2.x, a0);  a1 = fmaf(f4.y, v2.y, a1);
            a0 = fmaf(f5.x, v2.y, a0);  a1 = fmaf(f5.y, v3.x, a1);
            a0 = fmaf(f6.x, v3.x, a0);  a1 = fmaf(f6.y, v3.y, a1);
            a0 = fmaf(f7.x, v3.y, a0);  a1 = fmaf(f7.y, v4.x, a1);
            a0 = fmaf(f8.x, v4.x, a0);  a1 = fmaf(f8.y, v4.y, a1);
            acc[c][0] = a0; acc[c][1] = a1;
        }

        // 4) store staged row into the other buffer; single barrier per iter
        if (i < KK - 1) {
            *(float4*)&xs[buf ^ 1][cstage][lane32 << 2] = s0;
            *(float4*)&xs[buf ^ 1][cstage][(lane32 + 32) << 2] = s1;
            if (lane32 < 2) *(float4*)&xs[buf ^ 1][cstage][(lane32 + 64) << 2] = s2;
        }
        __syncthreads();
    }

    #pragma unroll
    for (int c = 0; c < 4; ++c) {
        *(float2*)(out + ((size_t)(n * CC + (cg << 2) + c) * HH + h) * WW + w0) =
            make_float2(acc[c][0], acc[c][1]);
    }
}

extern "C" void kernel_launch(void* const* d_in, const int* in_sizes, int n_in,
                              void* d_out, int out_size, void* d_ws, size_t ws_size,
                              hipStream_t stream) {
    const float* x  = (const float*)d_in[0];
    const float* f  = (const float*)d_in[1];
    const float* fb = (const float*)d_in[2];
    float* o = (float*)d_out;
    hipLaunchKernelGGL(dynfilter_kernel, dim3(1024), dim3(256), 0, stream,
                       x, f, fb, o);
}